// Round 8
// baseline (428.392 us; speedup 1.0000x reference)
//
#include <hip/hip_runtime.h>
#include <hip/hip_bf16.h>

// Problem constants (from reference): N=100000, F_IN=HID=256, E=800000, G=256
#define HID 256
#define NGRAPH 256

typedef __bf16 bf16_t;
typedef __attribute__((ext_vector_type(8))) __bf16 bf16x8;
typedef __attribute__((ext_vector_type(4))) __bf16 bf16x4;
typedef __attribute__((ext_vector_type(4))) float f32x4;

// ---------------------------------------------------------------------------
// CSR build (no hipMemsetAsync: zero via kernel; rowptr via parallel 3-pass scan)
// ---------------------------------------------------------------------------
__global__ void zero_int_kernel(int* __restrict__ p, int n) {
    int i = blockIdx.x * blockDim.x + threadIdx.x;
    if (i < n) p[i] = 0;
}

__global__ void count_deg_kernel(const int* __restrict__ ei, int E, int* __restrict__ deg) {
    int e = blockIdx.x * blockDim.x + threadIdx.x;
    if (e >= E) return;
    int dst = ei[E + e];
    atomicAdd(&deg[dst], 1);
}

#define SCHUNK 512

__global__ __launch_bounds__(256) void scan_pass1_kernel(
    const int* __restrict__ deg, int N, int* __restrict__ bsum) {
    __shared__ int red[256];
    int b = blockIdx.x, t = threadIdx.x;
    int i0 = b * SCHUNK + 2 * t;
    int v = 0;
    if (i0 < N) v += deg[i0];
    if (i0 + 1 < N) v += deg[i0 + 1];
    red[t] = v;
    __syncthreads();
    for (int s = 128; s > 0; s >>= 1) {
        if (t < s) red[t] += red[t + s];
        __syncthreads();
    }
    if (t == 0) bsum[b] = red[0];
}

__global__ __launch_bounds__(256) void scan_pass2_kernel(
    const int* __restrict__ bsum, int NB, int* __restrict__ boff) {
    __shared__ int s[256];
    int t = threadIdx.x;
    int v = (t < NB) ? bsum[t] : 0;
    s[t] = v;
    __syncthreads();
    for (int off = 1; off < 256; off <<= 1) {
        int x = s[t];
        if (t >= off) x += s[t - off];
        __syncthreads();
        s[t] = x;
        __syncthreads();
    }
    if (t < NB) boff[t] = s[t] - v;  // exclusive
}

__global__ __launch_bounds__(256) void scan_pass3_kernel(
    const int* __restrict__ deg, int N, const int* __restrict__ boff,
    int* __restrict__ rowptr, int* __restrict__ cursor, float* __restrict__ invd) {
    __shared__ int s[256];
    int b = blockIdx.x, t = threadIdx.x;
    int i0 = b * SCHUNK + 2 * t;
    int d0 = (i0 < N) ? deg[i0] : 0;
    int d1 = (i0 + 1 < N) ? deg[i0 + 1] : 0;
    int pair = d0 + d1;
    s[t] = pair;
    __syncthreads();
    for (int off = 1; off < 256; off <<= 1) {
        int x = s[t];
        if (t >= off) x += s[t - off];
        __syncthreads();
        s[t] = x;
        __syncthreads();
    }
    int excl = s[t] - pair + boff[b];
    if (i0 < N) {
        rowptr[i0] = excl;
        cursor[i0] = excl;
        invd[i0] = rsqrtf((float)d0 + 1.0f);
    }
    if (i0 + 1 < N) {
        int e1 = excl + d0;
        rowptr[i0 + 1] = e1;
        cursor[i0 + 1] = e1;
        invd[i0 + 1] = rsqrtf((float)d1 + 1.0f);
    }
}

__global__ void fill_csr_kernel(const int* __restrict__ ei, int E,
                                int* __restrict__ cursor, int* __restrict__ csr_src) {
    int e = blockIdx.x * blockDim.x + threadIdx.x;
    if (e >= E) return;
    int src = ei[e];
    int dst = ei[E + e];
    int pos = atomicAdd(&cursor[dst], 1);
    csr_src[pos] = src;
}

// ---------------------------------------------------------------------------
// W prep: W[k][n] (256x256 fp32, row-major) -> Wf fragment-major bf16:
//   Wf[((k0*16 + nt)*64 + kg*16 + m)*8 + j] = bf16( W[k0*32+kg*8+j][nt*16+m] )
// so a wave's B-fragment load (lane = kg*16+m) is ONE coalesced 1KB read.
// ---------------------------------------------------------------------------
__global__ __launch_bounds__(256) void wsplit_kernel(
    const float* __restrict__ W, bf16_t* __restrict__ Wf) {
    int idx = blockIdx.x * 256 + threadIdx.x;  // 0..65535
    float w = W[idx];
    int k = idx >> 8, n = idx & 255;
    int k0 = k >> 5, kg = (k >> 3) & 3, j = k & 7;
    int nt = n >> 4, m = n & 15;
    Wf[(size_t)(((k0 * 16 + nt) * 64) + kg * 16 + m) * 8 + j] = (bf16_t)w;
}

// ---------------------------------------------------------------------------
// MFMA GEMM: hs[i,:] = bf16( (X[i,:] @ W) * rowscale[i] )
// SPLIT=1: X fp32, 2-product hi/lo split (layer 1: acc = Ahi*B + Alo*B).
// SPLIT=0: X bf16 (layer-1 output h stored bf16), single product — half the
//          MFMAs and half the A-read traffic of the split path.
// Zero LDS / zero barriers; A-fragments direct from global in fragment layout;
// B-fragments from fragment-major Wf (one coalesced 1KB load per fragment).
// K-loop FULLY unrolled: all loads visible to the scheduler for deep hoisting
// (round-7 was latency-bound: MfmaUtil 11%, nothing else busy).
// MFMA layout facts (verified m89/m91): D col=lane&15, row=(lane>>4)*4+reg.
// A and B frags use the SAME k-index function => internal K-permutation cancels.
// ---------------------------------------------------------------------------
#define GBM 64

template <int SPLIT>
__global__ __launch_bounds__(256, 2) void gemm_mfma_kernel(
    const void* __restrict__ Xv, const bf16_t* __restrict__ Wf,
    const float* __restrict__ rowscale, bf16_t* __restrict__ out, int Nrows) {
    const int tid = threadIdx.x;
    const int wave = tid >> 6;
    const int lane = tid & 63;
    const int row0 = blockIdx.x * GBM;
    const int m = lane & 15;   // A-row / B-col / D-col within 16-tile
    const int kg = lane >> 4;  // k-group 0..3

    const int arow_raw = row0 + wave * 16 + m;
    const int arow = (arow_raw < Nrows) ? arow_raw : 0;  // clamp; stores masked

    f32x4 acc[16];
#pragma unroll
    for (int i = 0; i < 16; ++i) acc[i] = (f32x4){0.f, 0.f, 0.f, 0.f};

#pragma unroll
    for (int k0 = 0; k0 < 8; ++k0) {
        bf16x8 ah, al;
        if (SPLIT) {
            const float* xrow = (const float*)Xv + (size_t)arow * 256 + kg * 8;
            float4 xa = *(const float4*)&xrow[k0 * 32];
            float4 xb = *(const float4*)&xrow[k0 * 32 + 4];
            float xf[8] = {xa.x, xa.y, xa.z, xa.w, xb.x, xb.y, xb.z, xb.w};
#pragma unroll
            for (int q = 0; q < 8; ++q) {
                bf16_t hi = (bf16_t)xf[q];
                ah[q] = hi;
                al[q] = (bf16_t)(xf[q] - (float)hi);
            }
        } else {
            const bf16_t* xrow = (const bf16_t*)Xv + (size_t)arow * 256 + kg * 8;
            ah = *(const bf16x8*)&xrow[k0 * 32];
        }
        // ---- B fragments: 16 coalesced 1KB loads from fragment-major Wf ----
        const bf16_t* wfk = Wf + (size_t)(k0 * 16) * 64 * 8 + (size_t)lane * 8;
        bf16x8 bh[16];
#pragma unroll
        for (int nt = 0; nt < 16; ++nt)
            bh[nt] = *(const bf16x8*)(wfk + (size_t)nt * 64 * 8);
#pragma unroll
        for (int nt = 0; nt < 16; ++nt) {
            acc[nt] = __builtin_amdgcn_mfma_f32_16x16x32_bf16(ah, bh[nt], acc[nt], 0, 0, 0);
            if (SPLIT)
                acc[nt] = __builtin_amdgcn_mfma_f32_16x16x32_bf16(al, bh[nt], acc[nt], 0, 0, 0);
        }
    }

    // ---- epilogue: D col = lane&15, row = kg*4 + reg; bf16 output ----
    const int rbase = row0 + wave * 16 + kg * 4;
#pragma unroll
    for (int j = 0; j < 4; ++j) {
        int r = rbase + j;
        if (r < Nrows) {
            float sc = rowscale[r];
#pragma unroll
            for (int nt = 0; nt < 16; ++nt)
                out[(size_t)r * 256 + nt * 16 + m] = (bf16_t)(acc[nt][j] * sc);
        }
    }
}

// ---------------------------------------------------------------------------
// Aggregation: out[i,:] = relu( inv_d[i] * (hs[i,:] + sum_{src->i} hs[src,:]) + b )
// hs is bf16 (rows = 512B). One wave per node; lane owns 4 contiguous cols.
// 4-deep unroll keeps 4 independent gathers in flight. OutT: bf16 (layer 1,
// feeds gemm<0>) or fp32 (layer 2, final node_emb).
// ---------------------------------------------------------------------------
template <typename OutT>
__global__ __launch_bounds__(256) void gcn_aggregate_kernel(
    const bf16_t* __restrict__ hs, const int* __restrict__ rowptr,
    const int* __restrict__ deg, const int* __restrict__ csr_src,
    const float* __restrict__ inv_d, const float* __restrict__ bias,
    OutT* __restrict__ out, int N) {
    int gwid = (blockIdx.x * blockDim.x + threadIdx.x) >> 6;
    int lane = threadIdx.x & 63;
    if (gwid >= N) return;
    int base = rowptr[gwid];
    int len = deg[gwid];
    int c = lane * 4;

    bf16x4 sv = *(const bf16x4*)&hs[(size_t)gwid * 256 + c];
    float ax0 = (float)sv[0], ay0 = (float)sv[1], az0 = (float)sv[2], aw0 = (float)sv[3];
    float ax1 = 0.f, ay1 = 0.f, az1 = 0.f, aw1 = 0.f;
    float ax2 = 0.f, ay2 = 0.f, az2 = 0.f, aw2 = 0.f;
    float ax3 = 0.f, ay3 = 0.f, az3 = 0.f, aw3 = 0.f;
    int i = 0;
    for (; i + 4 <= len; i += 4) {
        int s0 = csr_src[base + i];
        int s1 = csr_src[base + i + 1];
        int s2 = csr_src[base + i + 2];
        int s3 = csr_src[base + i + 3];
        bf16x4 v0 = *(const bf16x4*)&hs[(size_t)s0 * 256 + c];
        bf16x4 v1 = *(const bf16x4*)&hs[(size_t)s1 * 256 + c];
        bf16x4 v2 = *(const bf16x4*)&hs[(size_t)s2 * 256 + c];
        bf16x4 v3 = *(const bf16x4*)&hs[(size_t)s3 * 256 + c];
        ax0 += (float)v0[0]; ay0 += (float)v0[1]; az0 += (float)v0[2]; aw0 += (float)v0[3];
        ax1 += (float)v1[0]; ay1 += (float)v1[1]; az1 += (float)v1[2]; aw1 += (float)v1[3];
        ax2 += (float)v2[0]; ay2 += (float)v2[1]; az2 += (float)v2[2]; aw2 += (float)v2[3];
        ax3 += (float)v3[0]; ay3 += (float)v3[1]; az3 += (float)v3[2]; aw3 += (float)v3[3];
    }
    for (; i < len; ++i) {
        int s = csr_src[base + i];
        bf16x4 v = *(const bf16x4*)&hs[(size_t)s * 256 + c];
        ax0 += (float)v[0]; ay0 += (float)v[1]; az0 += (float)v[2]; aw0 += (float)v[3];
    }
    float ax = (ax0 + ax1) + (ax2 + ax3);
    float ay = (ay0 + ay1) + (ay2 + ay3);
    float az = (az0 + az1) + (az2 + az3);
    float aw = (aw0 + aw1) + (aw2 + aw3);

    float sc = inv_d[gwid];
    float4 bb = *(const float4*)&bias[c];
    float ox = fmaxf(fmaf(ax, sc, bb.x), 0.f);
    float oy = fmaxf(fmaf(ay, sc, bb.y), 0.f);
    float oz = fmaxf(fmaf(az, sc, bb.z), 0.f);
    float ow = fmaxf(fmaf(aw, sc, bb.w), 0.f);
    if constexpr (sizeof(OutT) == 2) {
        bf16x4 o;
        o[0] = (bf16_t)ox; o[1] = (bf16_t)oy; o[2] = (bf16_t)oz; o[3] = (bf16_t)ow;
        *(bf16x4*)&out[(size_t)gwid * 256 + c] = o;
    } else {
        float4 o = {ox, oy, oz, ow};
        *(float4*)&out[(size_t)gwid * 256 + c] = o;
    }
}

// ---------------------------------------------------------------------------
// Graph boundaries from sorted batch: gstart[g] = first i with batch[i] >= g
// ---------------------------------------------------------------------------
__global__ void graph_bounds_kernel(const int* __restrict__ batch, int N, int G,
                                    int* __restrict__ gstart) {
    int i = blockIdx.x * blockDim.x + threadIdx.x;
    if (i > N) return;
    int cur = (i < N) ? batch[i] : G;
    int prev = (i == 0) ? -1 : batch[i - 1];
    for (int g = prev + 1; g <= cur; ++g) gstart[g] = i;
}

// One block per graph; thread j owns column j; 4-deep row unroll.
__global__ __launch_bounds__(256) void pool_mean_kernel(
    const float* __restrict__ emb, const int* __restrict__ gstart,
    float* __restrict__ gemb) {
    int g = blockIdx.x;
    int j = threadIdx.x;
    int s = gstart[g], e = gstart[g + 1];
    float s0 = 0.f, s1 = 0.f, s2 = 0.f, s3 = 0.f;
    int n = s;
    for (; n + 4 <= e; n += 4) {
        s0 += emb[(size_t)n * 256 + j];
        s1 += emb[(size_t)(n + 1) * 256 + j];
        s2 += emb[(size_t)(n + 2) * 256 + j];
        s3 += emb[(size_t)(n + 3) * 256 + j];
    }
    for (; n < e; ++n) s0 += emb[(size_t)n * 256 + j];
    float sum = (s0 + s1) + (s2 + s3);
    float cnt = fmaxf((float)(e - s), 1.0f);
    gemb[g * 256 + j] = sum / cnt;
}

// hcls = relu(gemb @ Wc1 + bc1); Wc1 is (256,128) row-major
__global__ __launch_bounds__(128) void cls1_kernel(
    const float* __restrict__ gemb, const float* __restrict__ Wc1,
    const float* __restrict__ bc1, float* __restrict__ hcls) {
    int g = blockIdx.x;
    int j = threadIdx.x;  // 0..127
    float sum = bc1[j];
    for (int k = 0; k < 256; ++k) sum = fmaf(gemb[g * 256 + k], Wc1[k * 128 + j], sum);
    hcls[g * 128 + j] = fmaxf(sum, 0.f);
}

// logits = hcls @ Wc2 + bc2; Wc2 is (128,2) row-major
__global__ void cls2_kernel(const float* __restrict__ hcls, const float* __restrict__ Wc2,
                            const float* __restrict__ bc2, float* __restrict__ logits, int G) {
    int idx = blockIdx.x * blockDim.x + threadIdx.x;
    if (idx >= G * 2) return;
    int g = idx >> 1, c = idx & 1;
    float sum = bc2[c];
    for (int k = 0; k < 128; ++k) sum = fmaf(hcls[g * 128 + k], Wc2[k * 2 + c], sum);
    logits[idx] = sum;
}

// ---------------------------------------------------------------------------
extern "C" void kernel_launch(void* const* d_in, const int* in_sizes, int n_in,
                              void* d_out, int out_size, void* d_ws, size_t ws_size,
                              hipStream_t stream) {
    const float* x   = (const float*)d_in[0];
    const int*   ei  = (const int*)d_in[1];
    const int*   batch = (const int*)d_in[2];
    // d_in[3] = num_graphs (device scalar) — known statically: 256
    const float* W1  = (const float*)d_in[4];
    const float* b1  = (const float*)d_in[5];
    const float* W2  = (const float*)d_in[6];
    const float* b2  = (const float*)d_in[7];
    const float* Wc1 = (const float*)d_in[8];
    const float* bc1 = (const float*)d_in[9];
    const float* Wc2 = (const float*)d_in[10];
    const float* bc2 = (const float*)d_in[11];

    const int N = in_sizes[0] / HID;   // 100000
    const int E = in_sizes[1] / 2;     // 800000
    const int G = NGRAPH;              // 256

    float* logits   = (float*)d_out;                  // G*2
    float* node_out = (float*)d_out + (size_t)G * 2;  // N*HID final node_emb

    // workspace layout
    char* wsb = (char*)d_ws;
    size_t off = 0;
    auto alloc = [&](size_t bytes) -> void* {
        void* p = wsb + off;
        off += (bytes + 255) & ~(size_t)255;
        return p;
    };
    bf16_t* hs     = (bf16_t*)alloc((size_t)N * HID * 2);  // 51.2 MB (h@W scaled)
    bf16_t* hb     = (bf16_t*)alloc((size_t)N * HID * 2);  // 51.2 MB (layer-1 h, bf16)
    int*    rowptr = (int*)alloc((size_t)N * 4);
    int*    cursor = (int*)alloc((size_t)N * 4);
    int*    degi   = (int*)alloc((size_t)N * 4);
    int*    csr    = (int*)alloc((size_t)E * 4);
    float*  invd   = (float*)alloc((size_t)N * 4);
    int*    gstart = (int*)alloc((size_t)(G + 1) * 4);
    float*  gemb   = (float*)alloc((size_t)G * HID * 4);
    float*  hcls   = (float*)alloc((size_t)G * (HID / 2) * 4);
    int*    bsum   = (int*)alloc(256 * 4);
    int*    boff   = (int*)alloc(256 * 4);
    bf16_t* wf     = (bf16_t*)alloc((size_t)HID * HID * 2);  // 128 KB
    (void)ws_size; (void)n_in; (void)out_size;

    const int NB = (N + SCHUNK - 1) / SCHUNK;  // 196 scan blocks

    // ---- CSR build (all compute-kernel path; no memset nodes in the graph) ----
    zero_int_kernel<<<(N + 255) / 256, 256, 0, stream>>>(degi, N);
    count_deg_kernel<<<(E + 255) / 256, 256, 0, stream>>>(ei, E, degi);
    scan_pass1_kernel<<<NB, 256, 0, stream>>>(degi, N, bsum);
    scan_pass2_kernel<<<1, 256, 0, stream>>>(bsum, NB, boff);
    scan_pass3_kernel<<<NB, 256, 0, stream>>>(degi, N, boff, rowptr, cursor, invd);
    fill_csr_kernel<<<(E + 255) / 256, 256, 0, stream>>>(ei, E, cursor, csr);

    const int GB = (N + GBM - 1) / GBM;  // 1563 GEMM blocks

    // ---- layer 1: fp32 x -> split path ----
    wsplit_kernel<<<HID * HID / 256, 256, 0, stream>>>(W1, wf);
    gemm_mfma_kernel<1><<<GB, 256, 0, stream>>>(x, wf, invd, hs, N);
    gcn_aggregate_kernel<bf16_t><<<(N * 64 + 255) / 256, 256, 0, stream>>>(
        hs, rowptr, degi, csr, invd, b1, hb, N);          // h (bf16)

    // ---- layer 2: bf16 h -> single-product path ----
    wsplit_kernel<<<HID * HID / 256, 256, 0, stream>>>(W2, wf);
    gemm_mfma_kernel<0><<<GB, 256, 0, stream>>>(hb, wf, invd, hs, N);
    gcn_aggregate_kernel<float><<<(N * 64 + 255) / 256, 256, 0, stream>>>(
        hs, rowptr, degi, csr, invd, b2, node_out, N);    // node_emb (fp32)

    // ---- pooling + classifier ----
    graph_bounds_kernel<<<(N + 1 + 255) / 256, 256, 0, stream>>>(batch, N, G, gstart);
    pool_mean_kernel<<<G, 256, 0, stream>>>(node_out, gstart, gemb);
    cls1_kernel<<<G, 128, 0, stream>>>(gemb, Wc1, bc1, hcls);
    cls2_kernel<<<(G * 2 + 255) / 256, 256, 0, stream>>>(hcls, Wc2, bc2, logits, G);
}

// Round 9
// 383.013 us; speedup vs baseline: 1.1185x; 1.1185x over previous
//
#include <hip/hip_runtime.h>
#include <hip/hip_bf16.h>

// Problem constants (from reference): N=100000, F_IN=HID=256, E=800000, G=256
#define HID 256
#define NGRAPH 256

typedef __bf16 bf16_t;
typedef __attribute__((ext_vector_type(8))) __bf16 bf16x8;
typedef __attribute__((ext_vector_type(4))) __bf16 bf16x4;
typedef __attribute__((ext_vector_type(4))) float f32x4;

// ---------------------------------------------------------------------------
// CSR build (no hipMemsetAsync: zero via kernel; rowptr via parallel 3-pass scan)
// ---------------------------------------------------------------------------
__global__ void zero_int_kernel(int* __restrict__ p, int n) {
    int i = blockIdx.x * blockDim.x + threadIdx.x;
    if (i < n) p[i] = 0;
}

__global__ void count_deg_kernel(const int* __restrict__ ei, int E, int* __restrict__ deg) {
    int e = blockIdx.x * blockDim.x + threadIdx.x;
    if (e >= E) return;
    int dst = ei[E + e];
    atomicAdd(&deg[dst], 1);
}

#define SCHUNK 512

__global__ __launch_bounds__(256) void scan_pass1_kernel(
    const int* __restrict__ deg, int N, int* __restrict__ bsum) {
    __shared__ int red[256];
    int b = blockIdx.x, t = threadIdx.x;
    int i0 = b * SCHUNK + 2 * t;
    int v = 0;
    if (i0 < N) v += deg[i0];
    if (i0 + 1 < N) v += deg[i0 + 1];
    red[t] = v;
    __syncthreads();
    for (int s = 128; s > 0; s >>= 1) {
        if (t < s) red[t] += red[t + s];
        __syncthreads();
    }
    if (t == 0) bsum[b] = red[0];
}

__global__ __launch_bounds__(256) void scan_pass2_kernel(
    const int* __restrict__ bsum, int NB, int* __restrict__ boff) {
    __shared__ int s[256];
    int t = threadIdx.x;
    int v = (t < NB) ? bsum[t] : 0;
    s[t] = v;
    __syncthreads();
    for (int off = 1; off < 256; off <<= 1) {
        int x = s[t];
        if (t >= off) x += s[t - off];
        __syncthreads();
        s[t] = x;
        __syncthreads();
    }
    if (t < NB) boff[t] = s[t] - v;  // exclusive
}

__global__ __launch_bounds__(256) void scan_pass3_kernel(
    const int* __restrict__ deg, int N, const int* __restrict__ boff,
    int* __restrict__ rowptr, int* __restrict__ cursor, float* __restrict__ invd) {
    __shared__ int s[256];
    int b = blockIdx.x, t = threadIdx.x;
    int i0 = b * SCHUNK + 2 * t;
    int d0 = (i0 < N) ? deg[i0] : 0;
    int d1 = (i0 + 1 < N) ? deg[i0 + 1] : 0;
    int pair = d0 + d1;
    s[t] = pair;
    __syncthreads();
    for (int off = 1; off < 256; off <<= 1) {
        int x = s[t];
        if (t >= off) x += s[t - off];
        __syncthreads();
        s[t] = x;
        __syncthreads();
    }
    int excl = s[t] - pair + boff[b];
    if (i0 < N) {
        rowptr[i0] = excl;
        cursor[i0] = excl;
        invd[i0] = rsqrtf((float)d0 + 1.0f);
    }
    if (i0 + 1 < N) {
        int e1 = excl + d0;
        rowptr[i0 + 1] = e1;
        cursor[i0 + 1] = e1;
        invd[i0 + 1] = rsqrtf((float)d1 + 1.0f);
    }
}

__global__ void fill_csr_kernel(const int* __restrict__ ei, int E,
                                int* __restrict__ cursor, int* __restrict__ csr_src) {
    int e = blockIdx.x * blockDim.x + threadIdx.x;
    if (e >= E) return;
    int src = ei[e];
    int dst = ei[E + e];
    int pos = atomicAdd(&cursor[dst], 1);
    csr_src[pos] = src;
}

// ---------------------------------------------------------------------------
// W prep: W[k][n] (256x256 fp32, row-major) -> Wf fragment-major bf16:
//   Wf[((k0*16 + nt)*64 + kg*16 + m)*8 + j] = bf16( W[k0*32+kg*8+j][nt*16+m] )
// Linear in (k0, nt, lane, j) — so both the LDS staging copy and a wave's
// B-fragment read are perfectly contiguous.
// ---------------------------------------------------------------------------
__global__ __launch_bounds__(256) void wsplit_kernel(
    const float* __restrict__ W, bf16_t* __restrict__ Wf) {
    int idx = blockIdx.x * 256 + threadIdx.x;  // 0..65535
    float w = W[idx];
    int k = idx >> 8, n = idx & 255;
    int k0 = k >> 5, kg = (k >> 3) & 3, j = k & 7;
    int nt = n >> 4, m = n & 15;
    Wf[(size_t)(((k0 * 16 + nt) * 64) + kg * 16 + m) * 8 + j] = (bf16_t)w;
}

// ---------------------------------------------------------------------------
// MFMA GEMM: hs[i,:] = bf16( (X[i,:] @ W) * rowscale[i] )
// SPLIT=1: X fp32, 2-product hi/lo split.  SPLIT=0: X bf16, single product.
// Round-8 postmortem: SPLIT=0 ran at the same 86us as SPLIT=1 => the wall is
// the per-K-step B-fragment loads from L2/L3 (VGPR=56 regalloc serialized the
// 16-load batches against ~200-500cyc latency). Fix: stage Wf in LDS in two
// 64KB half-K chunks; B-fragments become ds_read_b128 (120cyc, lgkmcnt
// fine-grained pipelining, 2-way bank pattern = free). A-fragments for the
// chunk's 4 K-steps are pre-issued BEFORE staging so global latency hides
// under the stage + barrier. 64KB LDS -> 2 blocks/CU for cross-block overlap.
// MFMA layout facts (verified m89/m91): D col=lane&15, row=(lane>>4)*4+reg.
// A and B frags use the SAME k-index function => internal K-permutation cancels.
// ---------------------------------------------------------------------------
#define GBM 64

template <int SPLIT>
__global__ __launch_bounds__(256, 2) void gemm_mfma_kernel(
    const void* __restrict__ Xv, const bf16_t* __restrict__ Wf,
    const float* __restrict__ rowscale, bf16_t* __restrict__ out, int Nrows) {
    __shared__ bf16_t Blds[32768];  // 64 KB: half-K of fragment-major W

    const int tid = threadIdx.x;
    const int wave = tid >> 6;
    const int lane = tid & 63;
    const int row0 = blockIdx.x * GBM;
    const int m = lane & 15;   // A-row / B-col / D-col within 16-tile
    const int kg = lane >> 4;  // k-group 0..3

    const int arow_raw = row0 + wave * 16 + m;
    const int arow = (arow_raw < Nrows) ? arow_raw : 0;  // clamp; stores masked

    f32x4 acc[16];
#pragma unroll
    for (int i = 0; i < 16; ++i) acc[i] = (f32x4){0.f, 0.f, 0.f, 0.f};

#pragma unroll
    for (int c = 0; c < 2; ++c) {
        // ---- pre-issue this chunk's A loads (latency hides under staging) ----
        float4 xa0, xb0, xa1, xb1, xa2, xb2, xa3, xb3;  // SPLIT=1
        bf16x8 ah0, ah1, ah2, ah3;                       // SPLIT=0
        if (SPLIT) {
            const float* xr = (const float*)Xv + (size_t)arow * 256 + c * 128 + kg * 8;
            xa0 = *(const float4*)&xr[0];   xb0 = *(const float4*)&xr[4];
            xa1 = *(const float4*)&xr[32];  xb1 = *(const float4*)&xr[36];
            xa2 = *(const float4*)&xr[64];  xb2 = *(const float4*)&xr[68];
            xa3 = *(const float4*)&xr[96];  xb3 = *(const float4*)&xr[100];
        } else {
            const bf16_t* xr = (const bf16_t*)Xv + (size_t)arow * 256 + c * 128 + kg * 8;
            ah0 = *(const bf16x8*)&xr[0];
            ah1 = *(const bf16x8*)&xr[32];
            ah2 = *(const bf16x8*)&xr[64];
            ah3 = *(const bf16x8*)&xr[96];
        }

        // ---- stage 64KB W chunk into LDS (linear copy, coalesced) ----
        if (c) __syncthreads();  // chunk 0 fully consumed before overwrite
#pragma unroll
        for (int it = 0; it < 16; ++it)
            *(bf16x8*)&Blds[it * 2048 + tid * 8] =
                *(const bf16x8*)&Wf[c * 32768 + it * 2048 + tid * 8];
        __syncthreads();

        // ---- 4 K-steps from LDS ----
#pragma unroll
        for (int k0c = 0; k0c < 4; ++k0c) {
            bf16x8 ah, al;
            if (SPLIT) {
                float4 xa = (k0c == 0) ? xa0 : (k0c == 1) ? xa1 : (k0c == 2) ? xa2 : xa3;
                float4 xb = (k0c == 0) ? xb0 : (k0c == 1) ? xb1 : (k0c == 2) ? xb2 : xb3;
                float xf[8] = {xa.x, xa.y, xa.z, xa.w, xb.x, xb.y, xb.z, xb.w};
#pragma unroll
                for (int q = 0; q < 8; ++q) {
                    bf16_t hi = (bf16_t)xf[q];
                    ah[q] = hi;
                    al[q] = (bf16_t)(xf[q] - (float)hi);
                }
            } else {
                ah = (k0c == 0) ? ah0 : (k0c == 1) ? ah1 : (k0c == 2) ? ah2 : ah3;
            }
            bf16x8 bh[16];
#pragma unroll
            for (int nt = 0; nt < 16; ++nt)
                bh[nt] = *(const bf16x8*)&Blds[(k0c * 16 + nt) * 512 + lane * 8];
#pragma unroll
            for (int nt = 0; nt < 16; ++nt) {
                acc[nt] = __builtin_amdgcn_mfma_f32_16x16x32_bf16(ah, bh[nt], acc[nt], 0, 0, 0);
                if (SPLIT)
                    acc[nt] = __builtin_amdgcn_mfma_f32_16x16x32_bf16(al, bh[nt], acc[nt], 0, 0, 0);
            }
        }
    }

    // ---- epilogue: D col = lane&15, row = kg*4 + reg; bf16 output ----
    const int rbase = row0 + wave * 16 + kg * 4;
#pragma unroll
    for (int j = 0; j < 4; ++j) {
        int r = rbase + j;
        if (r < Nrows) {
            float sc = rowscale[r];
#pragma unroll
            for (int nt = 0; nt < 16; ++nt)
                out[(size_t)r * 256 + nt * 16 + m] = (bf16_t)(acc[nt][j] * sc);
        }
    }
}

// ---------------------------------------------------------------------------
// Aggregation: out[i,:] = relu( inv_d[i] * (hs[i,:] + sum_{src->i} hs[src,:]) + b )
// hs is bf16 (rows = 512B). One wave per node; lane owns 4 contiguous cols.
// 4-deep unroll keeps 4 independent gathers in flight. OutT: bf16 (layer 1,
// feeds gemm<0>) or fp32 (layer 2, final node_emb).
// ---------------------------------------------------------------------------
template <typename OutT>
__global__ __launch_bounds__(256) void gcn_aggregate_kernel(
    const bf16_t* __restrict__ hs, const int* __restrict__ rowptr,
    const int* __restrict__ deg, const int* __restrict__ csr_src,
    const float* __restrict__ inv_d, const float* __restrict__ bias,
    OutT* __restrict__ out, int N) {
    int gwid = (blockIdx.x * blockDim.x + threadIdx.x) >> 6;
    int lane = threadIdx.x & 63;
    if (gwid >= N) return;
    int base = rowptr[gwid];
    int len = deg[gwid];
    int c = lane * 4;

    bf16x4 sv = *(const bf16x4*)&hs[(size_t)gwid * 256 + c];
    float ax0 = (float)sv[0], ay0 = (float)sv[1], az0 = (float)sv[2], aw0 = (float)sv[3];
    float ax1 = 0.f, ay1 = 0.f, az1 = 0.f, aw1 = 0.f;
    float ax2 = 0.f, ay2 = 0.f, az2 = 0.f, aw2 = 0.f;
    float ax3 = 0.f, ay3 = 0.f, az3 = 0.f, aw3 = 0.f;
    int i = 0;
    for (; i + 4 <= len; i += 4) {
        int s0 = csr_src[base + i];
        int s1 = csr_src[base + i + 1];
        int s2 = csr_src[base + i + 2];
        int s3 = csr_src[base + i + 3];
        bf16x4 v0 = *(const bf16x4*)&hs[(size_t)s0 * 256 + c];
        bf16x4 v1 = *(const bf16x4*)&hs[(size_t)s1 * 256 + c];
        bf16x4 v2 = *(const bf16x4*)&hs[(size_t)s2 * 256 + c];
        bf16x4 v3 = *(const bf16x4*)&hs[(size_t)s3 * 256 + c];
        ax0 += (float)v0[0]; ay0 += (float)v0[1]; az0 += (float)v0[2]; aw0 += (float)v0[3];
        ax1 += (float)v1[0]; ay1 += (float)v1[1]; az1 += (float)v1[2]; aw1 += (float)v1[3];
        ax2 += (float)v2[0]; ay2 += (float)v2[1]; az2 += (float)v2[2]; aw2 += (float)v2[3];
        ax3 += (float)v3[0]; ay3 += (float)v3[1]; az3 += (float)v3[2]; aw3 += (float)v3[3];
    }
    for (; i < len; ++i) {
        int s = csr_src[base + i];
        bf16x4 v = *(const bf16x4*)&hs[(size_t)s * 256 + c];
        ax0 += (float)v[0]; ay0 += (float)v[1]; az0 += (float)v[2]; aw0 += (float)v[3];
    }
    float ax = (ax0 + ax1) + (ax2 + ax3);
    float ay = (ay0 + ay1) + (ay2 + ay3);
    float az = (az0 + az1) + (az2 + az3);
    float aw = (aw0 + aw1) + (aw2 + aw3);

    float sc = inv_d[gwid];
    float4 bb = *(const float4*)&bias[c];
    float ox = fmaxf(fmaf(ax, sc, bb.x), 0.f);
    float oy = fmaxf(fmaf(ay, sc, bb.y), 0.f);
    float oz = fmaxf(fmaf(az, sc, bb.z), 0.f);
    float ow = fmaxf(fmaf(aw, sc, bb.w), 0.f);
    if constexpr (sizeof(OutT) == 2) {
        bf16x4 o;
        o[0] = (bf16_t)ox; o[1] = (bf16_t)oy; o[2] = (bf16_t)oz; o[3] = (bf16_t)ow;
        *(bf16x4*)&out[(size_t)gwid * 256 + c] = o;
    } else {
        float4 o = {ox, oy, oz, ow};
        *(float4*)&out[(size_t)gwid * 256 + c] = o;
    }
}

// ---------------------------------------------------------------------------
// Graph boundaries from sorted batch: gstart[g] = first i with batch[i] >= g
// ---------------------------------------------------------------------------
__global__ void graph_bounds_kernel(const int* __restrict__ batch, int N, int G,
                                    int* __restrict__ gstart) {
    int i = blockIdx.x * blockDim.x + threadIdx.x;
    if (i > N) return;
    int cur = (i < N) ? batch[i] : G;
    int prev = (i == 0) ? -1 : batch[i - 1];
    for (int g = prev + 1; g <= cur; ++g) gstart[g] = i;
}

// One block per graph; thread j owns column j; 4-deep row unroll.
__global__ __launch_bounds__(256) void pool_mean_kernel(
    const float* __restrict__ emb, const int* __restrict__ gstart,
    float* __restrict__ gemb) {
    int g = blockIdx.x;
    int j = threadIdx.x;
    int s = gstart[g], e = gstart[g + 1];
    float s0 = 0.f, s1 = 0.f, s2 = 0.f, s3 = 0.f;
    int n = s;
    for (; n + 4 <= e; n += 4) {
        s0 += emb[(size_t)n * 256 + j];
        s1 += emb[(size_t)(n + 1) * 256 + j];
        s2 += emb[(size_t)(n + 2) * 256 + j];
        s3 += emb[(size_t)(n + 3) * 256 + j];
    }
    for (; n < e; ++n) s0 += emb[(size_t)n * 256 + j];
    float sum = (s0 + s1) + (s2 + s3);
    float cnt = fmaxf((float)(e - s), 1.0f);
    gemb[g * 256 + j] = sum / cnt;
}

// hcls = relu(gemb @ Wc1 + bc1); Wc1 is (256,128) row-major
__global__ __launch_bounds__(128) void cls1_kernel(
    const float* __restrict__ gemb, const float* __restrict__ Wc1,
    const float* __restrict__ bc1, float* __restrict__ hcls) {
    int g = blockIdx.x;
    int j = threadIdx.x;  // 0..127
    float sum = bc1[j];
    for (int k = 0; k < 256; ++k) sum = fmaf(gemb[g * 256 + k], Wc1[k * 128 + j], sum);
    hcls[g * 128 + j] = fmaxf(sum, 0.f);
}

// logits = hcls @ Wc2 + bc2; Wc2 is (128,2) row-major
__global__ void cls2_kernel(const float* __restrict__ hcls, const float* __restrict__ Wc2,
                            const float* __restrict__ bc2, float* __restrict__ logits, int G) {
    int idx = blockIdx.x * blockDim.x + threadIdx.x;
    if (idx >= G * 2) return;
    int g = idx >> 1, c = idx & 1;
    float sum = bc2[c];
    for (int k = 0; k < 128; ++k) sum = fmaf(hcls[g * 128 + k], Wc2[k * 2 + c], sum);
    logits[idx] = sum;
}

// ---------------------------------------------------------------------------
extern "C" void kernel_launch(void* const* d_in, const int* in_sizes, int n_in,
                              void* d_out, int out_size, void* d_ws, size_t ws_size,
                              hipStream_t stream) {
    const float* x   = (const float*)d_in[0];
    const int*   ei  = (const int*)d_in[1];
    const int*   batch = (const int*)d_in[2];
    // d_in[3] = num_graphs (device scalar) — known statically: 256
    const float* W1  = (const float*)d_in[4];
    const float* b1  = (const float*)d_in[5];
    const float* W2  = (const float*)d_in[6];
    const float* b2  = (const float*)d_in[7];
    const float* Wc1 = (const float*)d_in[8];
    const float* bc1 = (const float*)d_in[9];
    const float* Wc2 = (const float*)d_in[10];
    const float* bc2 = (const float*)d_in[11];

    const int N = in_sizes[0] / HID;   // 100000
    const int E = in_sizes[1] / 2;     // 800000
    const int G = NGRAPH;              // 256

    float* logits   = (float*)d_out;                  // G*2
    float* node_out = (float*)d_out + (size_t)G * 2;  // N*HID final node_emb

    // workspace layout
    char* wsb = (char*)d_ws;
    size_t off = 0;
    auto alloc = [&](size_t bytes) -> void* {
        void* p = wsb + off;
        off += (bytes + 255) & ~(size_t)255;
        return p;
    };
    bf16_t* hs     = (bf16_t*)alloc((size_t)N * HID * 2);  // 51.2 MB (h@W scaled)
    bf16_t* hb     = (bf16_t*)alloc((size_t)N * HID * 2);  // 51.2 MB (layer-1 h, bf16)
    int*    rowptr = (int*)alloc((size_t)N * 4);
    int*    cursor = (int*)alloc((size_t)N * 4);
    int*    degi   = (int*)alloc((size_t)N * 4);
    int*    csr    = (int*)alloc((size_t)E * 4);
    float*  invd   = (float*)alloc((size_t)N * 4);
    int*    gstart = (int*)alloc((size_t)(G + 1) * 4);
    float*  gemb   = (float*)alloc((size_t)G * HID * 4);
    float*  hcls   = (float*)alloc((size_t)G * (HID / 2) * 4);
    int*    bsum   = (int*)alloc(256 * 4);
    int*    boff   = (int*)alloc(256 * 4);
    bf16_t* wf     = (bf16_t*)alloc((size_t)HID * HID * 2);  // 128 KB
    (void)ws_size; (void)n_in; (void)out_size;

    const int NB = (N + SCHUNK - 1) / SCHUNK;  // 196 scan blocks

    // ---- CSR build (all compute-kernel path; no memset nodes in the graph) ----
    zero_int_kernel<<<(N + 255) / 256, 256, 0, stream>>>(degi, N);
    count_deg_kernel<<<(E + 255) / 256, 256, 0, stream>>>(ei, E, degi);
    scan_pass1_kernel<<<NB, 256, 0, stream>>>(degi, N, bsum);
    scan_pass2_kernel<<<1, 256, 0, stream>>>(bsum, NB, boff);
    scan_pass3_kernel<<<NB, 256, 0, stream>>>(degi, N, boff, rowptr, cursor, invd);
    fill_csr_kernel<<<(E + 255) / 256, 256, 0, stream>>>(ei, E, cursor, csr);

    const int GB = (N + GBM - 1) / GBM;  // 1563 GEMM blocks

    // ---- layer 1: fp32 x -> split path ----
    wsplit_kernel<<<HID * HID / 256, 256, 0, stream>>>(W1, wf);
    gemm_mfma_kernel<1><<<GB, 256, 0, stream>>>(x, wf, invd, hs, N);
    gcn_aggregate_kernel<bf16_t><<<(N * 64 + 255) / 256, 256, 0, stream>>>(
        hs, rowptr, degi, csr, invd, b1, hb, N);          // h (bf16)

    // ---- layer 2: bf16 h -> single-product path ----
    wsplit_kernel<<<HID * HID / 256, 256, 0, stream>>>(W2, wf);
    gemm_mfma_kernel<0><<<GB, 256, 0, stream>>>(hb, wf, invd, hs, N);
    gcn_aggregate_kernel<float><<<(N * 64 + 255) / 256, 256, 0, stream>>>(
        hs, rowptr, degi, csr, invd, b2, node_out, N);    // node_emb (fp32)

    // ---- pooling + classifier ----
    graph_bounds_kernel<<<(N + 1 + 255) / 256, 256, 0, stream>>>(batch, N, G, gstart);
    pool_mean_kernel<<<G, 256, 0, stream>>>(node_out, gstart, gemb);
    cls1_kernel<<<G, 128, 0, stream>>>(gemb, Wc1, bc1, hcls);
    cls2_kernel<<<(G * 2 + 255) / 256, 256, 0, stream>>>(hcls, Wc2, bc2, logits, G);
}